// Round 4
// baseline (592.303 us; speedup 1.0000x reference)
//
#include <hip/hip_runtime.h>
#include <stdint.h>

// B=1024, T=65, D=H=512. Only the SLOW critic feeds the output.
//   prep:  W1s,W2s -> bf16 transposed Wt[n][k] (tiled LDS transpose); zero tarval
//   gemm1: H1 = silu(feat @ W1s + b1s)          barrier-free streaming MFMA
//   gemm2: tarval = silu(H1 @ W2s + b2s) @ W3s  barrier-free streaming MFMA
//   scan:  lambda-return reverse scan -> out (f32)
// Weights (512KB bf16) are L2-resident per XCD -> no LDS staging needed;
// K-loop has NO barriers / NO LDS -> no bank conflicts, compiler pipelines.

#define MROWS 66560   // 1024*65
#define RBLK 520      // MROWS/128
#define LAMF 0.95f
#define DISCF ((float)(1.0 - 1.0 / 333.0))

typedef __attribute__((ext_vector_type(8))) __bf16 bf16x8;
typedef __attribute__((ext_vector_type(4))) float f32x4;

__device__ __forceinline__ unsigned short f2bf(float f) {
  unsigned int u = __float_as_uint(f);
  return (unsigned short)((u + 0x7FFFu + ((u >> 16) & 1u)) >> 16);
}
__device__ __forceinline__ float silu_f(float x) { return x / (1.0f + __expf(-x)); }

// ---------------- prep: tiled transpose W->Wt bf16, zero tarval --------------
__global__ __launch_bounds__(256) void prep_kernel(
    const float* __restrict__ W1, const float* __restrict__ W2,
    unsigned short* __restrict__ Wt1, unsigned short* __restrict__ Wt2,
    float* __restrict__ tarval) {
  int b = blockIdx.x;
  if (b < 128) {
    const float* W = (b < 64) ? W1 : W2;
    unsigned short* Wt = (b < 64) ? Wt1 : Wt2;
    int tb = b & 63;
    int tk = (tb >> 3) * 64;   // row origin in W (k)
    int tn = (tb & 7) * 64;    // col origin in W (n)
    __shared__ float tile[64][65];
    int tx = threadIdx.x & 63;
    int ty4 = threadIdx.x >> 6;
#pragma unroll
    for (int i = 0; i < 16; ++i) {
      int row = ty4 * 16 + i;
      tile[row][tx] = W[(size_t)(tk + row) * 512 + tn + tx];  // coalesced read
    }
    __syncthreads();
#pragma unroll
    for (int i = 0; i < 16; ++i) {
      int nrow = ty4 * 16 + i;  // n within tile
      Wt[(size_t)(tn + nrow) * 512 + tk + tx] = f2bf(tile[tx][nrow]);  // coalesced write
    }
  } else {
    int id = (b - 128) * 256 + threadIdx.x;
#pragma unroll
    for (int i = 0; i < 17; ++i) {
      int idx = id + i * 4096;
      if (idx < MROWS) tarval[idx] = 0.0f;
    }
  }
}

// XCD-aware tile mapping: the 4 col-blocks sharing one A row-tile are
// consecutive in per-XCD dispatch order -> A tile + W stay in that XCD's L2.
__device__ __forceinline__ void tile_map(int bid, int& rb, int& cb) {
  int xcd = bid & 7;
  int idx = bid >> 3;        // 0..259 per XCD
  rb = xcd * 65 + (idx >> 2);
  cb = idx & 3;
}

// ---------------- GEMM1: A=feat f32 (reg convert), B=Wt1 bf16, streaming ----
__global__ __launch_bounds__(256) void gemm1_kernel(
    const float* __restrict__ A, const unsigned short* __restrict__ Bt,
    const float* __restrict__ bias, unsigned short* __restrict__ Hout) {
  int rb, cb; tile_map(blockIdx.x, rb, cb);
  const int m0 = rb * 128, n0 = cb * 128;
  const int lane = threadIdx.x & 63, w = threadIdx.x >> 6;
  const int wr = w >> 1, wc = w & 1;
  const int q = lane >> 4, r = lane & 15;

  // per-lane element offsets (compile-time-indexed arrays only)
  unsigned int aoff[4], boff[4];
#pragma unroll
  for (int m = 0; m < 4; ++m)
    aoff[m] = (unsigned int)(m0 + wr * 64 + m * 16 + r) * 512u + q * 8u;
#pragma unroll
  for (int n = 0; n < 4; ++n)
    boff[n] = (unsigned int)(n0 + wc * 64 + n * 16 + r) * 512u + q * 8u;

  f32x4 acc[4][4] = {};

#pragma unroll 4
  for (int k0 = 0; k0 < 512; k0 += 32) {
    bf16x8 af[4], bfr[4];
#pragma unroll
    for (int n = 0; n < 4; ++n)
      bfr[n] = *(const bf16x8*)(Bt + boff[n] + k0);
#pragma unroll
    for (int m = 0; m < 4; ++m) {
      f32x4 lo = *(const f32x4*)(A + aoff[m] + k0);
      f32x4 hi = *(const f32x4*)(A + aoff[m] + k0 + 4);
      af[m][0] = (__bf16)lo[0]; af[m][1] = (__bf16)lo[1];
      af[m][2] = (__bf16)lo[2]; af[m][3] = (__bf16)lo[3];
      af[m][4] = (__bf16)hi[0]; af[m][5] = (__bf16)hi[1];
      af[m][6] = (__bf16)hi[2]; af[m][7] = (__bf16)hi[3];
    }
#pragma unroll
    for (int m = 0; m < 4; ++m)
#pragma unroll
      for (int n = 0; n < 4; ++n)
        acc[m][n] = __builtin_amdgcn_mfma_f32_16x16x32_bf16(af[m], bfr[n], acc[m][n], 0, 0, 0);
  }

  // epilogue: bias + silu -> bf16 H1 (layout math identical to validated r3)
#pragma unroll
  for (int n = 0; n < 4; ++n) {
    const int col = n0 + wc * 64 + n * 16 + r;
    const float bn = bias[col];
#pragma unroll
    for (int m = 0; m < 4; ++m) {
      const int rbase = m0 + wr * 64 + m * 16 + q * 4;
#pragma unroll
      for (int i = 0; i < 4; ++i)
        Hout[(size_t)(rbase + i) * 512 + col] = f2bf(silu_f(acc[m][n][i] + bn));
    }
  }
}

// ---------------- GEMM2: A=H1 bf16, B=Wt2 bf16, fused W3 reduce, streaming --
__global__ __launch_bounds__(256) void gemm2_kernel(
    const unsigned short* __restrict__ A, const unsigned short* __restrict__ Bt,
    const float* __restrict__ bias, const float* __restrict__ W3,
    float* __restrict__ tarval) {
  int rb, cb; tile_map(blockIdx.x, rb, cb);
  const int m0 = rb * 128, n0 = cb * 128;
  const int lane = threadIdx.x & 63, w = threadIdx.x >> 6;
  const int wr = w >> 1, wc = w & 1;
  const int q = lane >> 4, r = lane & 15;

  unsigned int aoff[4], boff[4];
#pragma unroll
  for (int m = 0; m < 4; ++m)
    aoff[m] = (unsigned int)(m0 + wr * 64 + m * 16 + r) * 512u + q * 8u;
#pragma unroll
  for (int n = 0; n < 4; ++n)
    boff[n] = (unsigned int)(n0 + wc * 64 + n * 16 + r) * 512u + q * 8u;

  f32x4 acc[4][4] = {};

#pragma unroll 4
  for (int k0 = 0; k0 < 512; k0 += 32) {
    bf16x8 af[4], bfr[4];
#pragma unroll
    for (int m = 0; m < 4; ++m)
      af[m] = *(const bf16x8*)(A + aoff[m] + k0);
#pragma unroll
    for (int n = 0; n < 4; ++n)
      bfr[n] = *(const bf16x8*)(Bt + boff[n] + k0);
#pragma unroll
    for (int m = 0; m < 4; ++m)
#pragma unroll
      for (int n = 0; n < 4; ++n)
        acc[m][n] = __builtin_amdgcn_mfma_f32_16x16x32_bf16(af[m], bfr[n], acc[m][n], 0, 0, 0);
  }

  // epilogue: silu(acc+b2) * W3[col], 16-lane shuffle reduce, atomic per row
#pragma unroll
  for (int m = 0; m < 4; ++m) {
    float ps0 = 0.f, ps1 = 0.f, ps2 = 0.f, ps3 = 0.f;
#pragma unroll
    for (int n = 0; n < 4; ++n) {
      const int col = n0 + wc * 64 + n * 16 + r;
      const float bn = bias[col];
      const float w3 = W3[col];
      ps0 += silu_f(acc[m][n][0] + bn) * w3;
      ps1 += silu_f(acc[m][n][1] + bn) * w3;
      ps2 += silu_f(acc[m][n][2] + bn) * w3;
      ps3 += silu_f(acc[m][n][3] + bn) * w3;
    }
    float ps[4] = {ps0, ps1, ps2, ps3};
#pragma unroll
    for (int i = 0; i < 4; ++i) {
      float v = ps[i];
      v += __shfl_xor(v, 1);
      v += __shfl_xor(v, 2);
      v += __shfl_xor(v, 4);
      v += __shfl_xor(v, 8);
      if (r == 0) {
        int row = m0 + wr * 64 + m * 16 + q * 4 + i;
        atomicAdd(&tarval[row], v);
      }
    }
  }
}

// ---------------- scan: lambda-return reverse scan per batch row ------------
__global__ __launch_bounds__(64) void scan_kernel(
    const float* __restrict__ tarval, const float* __restrict__ reward,
    const float* __restrict__ cont, const float* __restrict__ voffset,
    const float* __restrict__ vscale, const float* __restrict__ b3,
    float* __restrict__ out) {
  __shared__ float tv[64];
  __shared__ float ret[64];
  const int b = blockIdx.x, t = threadIdx.x;  // t = 0..63 maps to orig t+1
  tv[t] = (tarval[b * 65 + 1 + t] + b3[0]) * vscale[0] + voffset[0];
  __syncthreads();
  if (t == 0) {
    float carry = tv[63];  // boot = tarval[:, -1]
    for (int j = 63; j >= 0; --j) {
      const int tt = j + 1;
      const float disc = cont[b * 65 + tt] * DISCF;
      const float r = reward[b * 65 + tt] + disc * ((1.0f - LAMF) * tv[j] + LAMF * carry);
      ret[j] = r;
      carry = r;
    }
  }
  __syncthreads();
  out[b * 64 + t] = ret[t];   // f32 output
}

extern "C" void kernel_launch(void* const* d_in, const int* in_sizes, int n_in,
                              void* d_out, int out_size, void* d_ws, size_t ws_size,
                              hipStream_t stream) {
  const float* feat    = (const float*)d_in[0];
  const float* reward  = (const float*)d_in[1];
  const float* cont    = (const float*)d_in[2];
  const float* voffset = (const float*)d_in[3];
  const float* vscale  = (const float*)d_in[4];
  const float* W1s = (const float*)d_in[11];
  const float* b1s = (const float*)d_in[12];
  const float* W2s = (const float*)d_in[13];
  const float* b2s = (const float*)d_in[14];
  const float* W3s = (const float*)d_in[15];
  const float* b3s = (const float*)d_in[16];

  char* ws = (char*)d_ws;
  unsigned short* Wt1 = (unsigned short*)ws;                   // 512 KB
  unsigned short* Wt2 = (unsigned short*)(ws + (512u << 10));  // 512 KB
  float* tarval       = (float*)(ws + (1024u << 10));          // 266 240 B
  unsigned short* H1  = (unsigned short*)(ws + (2048u << 10)); // 68 157 440 B

  prep_kernel<<<144, 256, 0, stream>>>(W1s, W2s, Wt1, Wt2, tarval);
  gemm1_kernel<<<RBLK * 4, 256, 0, stream>>>(feat, Wt1, b1s, H1);
  gemm2_kernel<<<RBLK * 4, 256, 0, stream>>>(H1, Wt2, b2s, W3s, tarval);
  scan_kernel<<<1024, 64, 0, stream>>>(tarval, reward, cont, voffset, vscale, b3s,
                                       (float*)d_out);
}

// Round 5
// 375.770 us; speedup vs baseline: 1.5762x; 1.5762x over previous
//
#include <hip/hip_runtime.h>
#include <stdint.h>

// B=1024, T=65, D=H=512. Only the SLOW critic feeds the output.
//   prep:  W1s,W2s -> bf16 transposed Wt[n][k]; zero tarval
//   gemm1: H1 = silu(feat @ W1s + b1s)           128x128 tile, dbuf LDS, prefetch
//   gemm2: tarval = silu(H1 @ W2s + b2s) @ W3s   same structure, fused W3 reduce
//   scan:  lambda-return reverse scan -> out (f32)
// K-loop = T3 "minimum 2-phase": issue next-tile stage BEFORE current compute,
// ONE barrier per K-step, double-buffered LDS (64KB -> 2 blocks/CU).

#define MROWS 66560   // 1024*65
#define RBLK 520      // MROWS/128
#define LAMF 0.95f
#define DISCF ((float)(1.0 - 1.0 / 333.0))

typedef __attribute__((ext_vector_type(8))) __bf16 bf16x8;
typedef __attribute__((ext_vector_type(4))) float f32x4;
typedef __attribute__((ext_vector_type(4))) unsigned int u32x4;

__device__ __forceinline__ unsigned short f2bf(float f) {
  unsigned int u = __float_as_uint(f);
  return (unsigned short)((u + 0x7FFFu + ((u >> 16) & 1u)) >> 16);
}
__device__ __forceinline__ float silu_f(float x) { return x / (1.0f + __expf(-x)); }

__device__ __forceinline__ void gload_lds16(const void* g, void* l) {
  __builtin_amdgcn_global_load_lds(
      (const __attribute__((address_space(1))) void*)g,
      (__attribute__((address_space(3))) void*)l, 16, 0, 0);
}

// ---------------- prep: tiled transpose W->Wt bf16, zero tarval --------------
__global__ __launch_bounds__(256) void prep_kernel(
    const float* __restrict__ W1, const float* __restrict__ W2,
    unsigned short* __restrict__ Wt1, unsigned short* __restrict__ Wt2,
    float* __restrict__ tarval) {
  int b = blockIdx.x;
  if (b < 128) {
    const float* W = (b < 64) ? W1 : W2;
    unsigned short* Wt = (b < 64) ? Wt1 : Wt2;
    int tb = b & 63;
    int tk = (tb >> 3) * 64;   // row origin in W (k)
    int tn = (tb & 7) * 64;    // col origin in W (n)
    __shared__ float tile[64][65];
    int tx = threadIdx.x & 63;
    int ty4 = threadIdx.x >> 6;
#pragma unroll
    for (int i = 0; i < 16; ++i) {
      int row = ty4 * 16 + i;
      tile[row][tx] = W[(size_t)(tk + row) * 512 + tn + tx];  // coalesced read
    }
    __syncthreads();
#pragma unroll
    for (int i = 0; i < 16; ++i) {
      int nrow = ty4 * 16 + i;  // n within tile
      Wt[(size_t)(tn + nrow) * 512 + tk + tx] = f2bf(tile[tx][nrow]);  // coalesced write
    }
  } else {
    int id = (b - 128) * 256 + threadIdx.x;
#pragma unroll
    for (int i = 0; i < 17; ++i) {
      int idx = id + i * 4096;
      if (idx < MROWS) tarval[idx] = 0.0f;
    }
  }
}

// XCD-aware tile mapping: the 4 col-blocks sharing one A row-tile are
// consecutive in per-XCD dispatch order -> A tile + W stay in that XCD's L2.
__device__ __forceinline__ void tile_map(int bid, int& rb, int& cb) {
  int xcd = bid & 7;
  int idx = bid >> 3;        // 0..259 per XCD
  rb = xcd * 65 + (idx >> 2);
  cb = idx & 3;
}

// ---------------- GEMM1: A=feat f32 (reg-staged convert), B=Wt1 bf16 --------
__global__ __launch_bounds__(256) void gemm1_kernel(
    const float* __restrict__ A, const unsigned short* __restrict__ Bt,
    const float* __restrict__ bias, unsigned short* __restrict__ Hout) {
  __shared__ __align__(16) unsigned char lds[65536];  // [2][A 16K | B 16K]

  int rb, cb; tile_map(blockIdx.x, rb, cb);
  const int m0 = rb * 128, n0 = cb * 128;
  const int tid = threadIdx.x;
  const int lane = tid & 63, w = tid >> 6;
  const int wr = w >> 1, wc = w & 1;
  const int q = lane >> 4, r = lane & 15;

  f32x4 acc[4][4] = {};
  f32x4 pa[8];

  // ---- prologue: stage ks=0 into buf0 ----
  {
    // A f32 -> regs (issued first)
#pragma unroll
    for (int i = 0; i < 4; ++i) {
      int L = (i * 256 + tid) * 16;
      int row = L >> 7, kb = L & 127;
      const float* src = A + (size_t)(m0 + row) * 512 + (kb >> 1);
      pa[2 * i]     = *(const f32x4*)(src);
      pa[2 * i + 1] = *(const f32x4*)(src + 4);
    }
    // B via global_load_lds
    unsigned char* Bl = lds + 16384;
    const int base = w * 1024;
#pragma unroll
    for (int i = 0; i < 4; ++i) {
      int L = i * 4096 + base + lane * 16;
      int row = L >> 7, kb = L & 127;
      gload_lds16((const void*)(Bt + (size_t)(n0 + row) * 512 + (kb >> 1)),
                  (void*)(Bl + i * 4096 + base));
    }
    // convert + ds_write A
    unsigned char* Al = lds;
#pragma unroll
    for (int i = 0; i < 4; ++i) {
      int L = (i * 256 + tid) * 16;
      union { unsigned short h[8]; u32x4 u; } p;
      p.h[0] = f2bf(pa[2*i][0]); p.h[1] = f2bf(pa[2*i][1]);
      p.h[2] = f2bf(pa[2*i][2]); p.h[3] = f2bf(pa[2*i][3]);
      p.h[4] = f2bf(pa[2*i+1][0]); p.h[5] = f2bf(pa[2*i+1][1]);
      p.h[6] = f2bf(pa[2*i+1][2]); p.h[7] = f2bf(pa[2*i+1][3]);
      *(u32x4*)(Al + L) = p.u;
    }
  }
  __syncthreads();

  // ---- main loop: compute buf[t&1], prefetch t+1 into buf[(t+1)&1] ----
#pragma unroll
  for (int t = 0; t < 8; ++t) {
    unsigned char* Acur = lds + (t & 1) * 32768;
    unsigned char* Bcur = Acur + 16384;
    unsigned char* Anx  = lds + ((t + 1) & 1) * 32768;
    unsigned char* Bnx  = Anx + 16384;

    if (t < 7) {
      const int ks = (t + 1) * 64;
      // A f32 -> regs first (so its wait later is vmcnt(4), not 0)
#pragma unroll
      for (int i = 0; i < 4; ++i) {
        int L = (i * 256 + tid) * 16;
        int row = L >> 7, kb = L & 127;
        const float* src = A + (size_t)(m0 + row) * 512 + ks + (kb >> 1);
        pa[2 * i]     = *(const f32x4*)(src);
        pa[2 * i + 1] = *(const f32x4*)(src + 4);
      }
      const int base = w * 1024;
#pragma unroll
      for (int i = 0; i < 4; ++i) {
        int L = i * 4096 + base + lane * 16;
        int row = L >> 7, kb = L & 127;
        gload_lds16((const void*)(Bt + (size_t)(n0 + row) * 512 + ks + (kb >> 1)),
                    (void*)(Bnx + i * 4096 + base));
      }
    }

    // compute current tile
#pragma unroll
    for (int kk = 0; kk < 2; ++kk) {
      bf16x8 af[4], bfr[4];
      const int kbyte = kk * 64 + q * 16;
#pragma unroll
      for (int m = 0; m < 4; ++m)
        af[m] = *(const bf16x8*)(Acur + (wr * 64 + m * 16 + r) * 128 + kbyte);
#pragma unroll
      for (int n = 0; n < 4; ++n)
        bfr[n] = *(const bf16x8*)(Bcur + (wc * 64 + n * 16 + r) * 128 + kbyte);
#pragma unroll
      for (int m = 0; m < 4; ++m)
#pragma unroll
        for (int n = 0; n < 4; ++n)
          acc[m][n] = __builtin_amdgcn_mfma_f32_16x16x32_bf16(af[m], bfr[n], acc[m][n], 0, 0, 0);
    }

    if (t < 7) {
      // convert + ds_write next A tile (waits pa loads; B gloads still in flight)
#pragma unroll
      for (int i = 0; i < 4; ++i) {
        int L = (i * 256 + tid) * 16;
        union { unsigned short h[8]; u32x4 u; } p;
        p.h[0] = f2bf(pa[2*i][0]); p.h[1] = f2bf(pa[2*i][1]);
        p.h[2] = f2bf(pa[2*i][2]); p.h[3] = f2bf(pa[2*i][3]);
        p.h[4] = f2bf(pa[2*i+1][0]); p.h[5] = f2bf(pa[2*i+1][1]);
        p.h[6] = f2bf(pa[2*i+1][2]); p.h[7] = f2bf(pa[2*i+1][3]);
        *(u32x4*)(Anx + L) = p.u;
      }
    }
    __syncthreads();   // drains vmcnt+lgkm: next buffer fully staged
  }

  // epilogue: bias + silu -> bf16 H1
#pragma unroll
  for (int n = 0; n < 4; ++n) {
    const int col = n0 + wc * 64 + n * 16 + r;
    const float bn = bias[col];
#pragma unroll
    for (int m = 0; m < 4; ++m) {
      const int rbase = m0 + wr * 64 + m * 16 + q * 4;
#pragma unroll
      for (int i = 0; i < 4; ++i)
        Hout[(size_t)(rbase + i) * 512 + col] = f2bf(silu_f(acc[m][n][i] + bn));
    }
  }
}

// ---------------- GEMM2: A=H1 bf16, B=Wt2 bf16, fused W3 reduce -------------
__global__ __launch_bounds__(256) void gemm2_kernel(
    const unsigned short* __restrict__ A, const unsigned short* __restrict__ Bt,
    const float* __restrict__ bias, const float* __restrict__ W3,
    float* __restrict__ tarval) {
  __shared__ __align__(16) unsigned char lds[65536];  // [2][A 16K | B 16K]

  int rb, cb; tile_map(blockIdx.x, rb, cb);
  const int m0 = rb * 128, n0 = cb * 128;
  const int tid = threadIdx.x;
  const int lane = tid & 63, w = tid >> 6;
  const int wr = w >> 1, wc = w & 1;
  const int q = lane >> 4, r = lane & 15;

  f32x4 acc[4][4] = {};
  const int base = w * 1024;

  // ---- prologue: stage ks=0 into buf0 (all via global_load_lds) ----
  {
    unsigned char* Al = lds;
    unsigned char* Bl = lds + 16384;
#pragma unroll
    for (int i = 0; i < 4; ++i) {
      int L = i * 4096 + base + lane * 16;
      int row = L >> 7, kb = L & 127;
      gload_lds16((const void*)(A + (size_t)(m0 + row) * 512 + (kb >> 1)),
                  (void*)(Al + i * 4096 + base));
      gload_lds16((const void*)(Bt + (size_t)(n0 + row) * 512 + (kb >> 1)),
                  (void*)(Bl + i * 4096 + base));
    }
  }
  __syncthreads();

#pragma unroll
  for (int t = 0; t < 8; ++t) {
    unsigned char* Acur = lds + (t & 1) * 32768;
    unsigned char* Bcur = Acur + 16384;
    unsigned char* Anx  = lds + ((t + 1) & 1) * 32768;
    unsigned char* Bnx  = Anx + 16384;

    if (t < 7) {
      const int ks = (t + 1) * 64;
#pragma unroll
      for (int i = 0; i < 4; ++i) {
        int L = i * 4096 + base + lane * 16;
        int row = L >> 7, kb = L & 127;
        gload_lds16((const void*)(A + (size_t)(m0 + row) * 512 + ks + (kb >> 1)),
                    (void*)(Anx + i * 4096 + base));
        gload_lds16((const void*)(Bt + (size_t)(n0 + row) * 512 + ks + (kb >> 1)),
                    (void*)(Bnx + i * 4096 + base));
      }
    }

#pragma unroll
    for (int kk = 0; kk < 2; ++kk) {
      bf16x8 af[4], bfr[4];
      const int kbyte = kk * 64 + q * 16;
#pragma unroll
      for (int m = 0; m < 4; ++m)
        af[m] = *(const bf16x8*)(Acur + (wr * 64 + m * 16 + r) * 128 + kbyte);
#pragma unroll
      for (int n = 0; n < 4; ++n)
        bfr[n] = *(const bf16x8*)(Bcur + (wc * 64 + n * 16 + r) * 128 + kbyte);
#pragma unroll
      for (int m = 0; m < 4; ++m)
#pragma unroll
        for (int n = 0; n < 4; ++n)
          acc[m][n] = __builtin_amdgcn_mfma_f32_16x16x32_bf16(af[m], bfr[n], acc[m][n], 0, 0, 0);
    }
    __syncthreads();
  }

  // epilogue: silu(acc+b2) * W3[col], 16-lane shuffle reduce, atomic per row
#pragma unroll
  for (int m = 0; m < 4; ++m) {
    float ps0 = 0.f, ps1 = 0.f, ps2 = 0.f, ps3 = 0.f;
#pragma unroll
    for (int n = 0; n < 4; ++n) {
      const int col = n0 + wc * 64 + n * 16 + r;
      const float bn = bias[col];
      const float w3 = W3[col];
      ps0 += silu_f(acc[m][n][0] + bn) * w3;
      ps1 += silu_f(acc[m][n][1] + bn) * w3;
      ps2 += silu_f(acc[m][n][2] + bn) * w3;
      ps3 += silu_f(acc[m][n][3] + bn) * w3;
    }
    float ps[4] = {ps0, ps1, ps2, ps3};
#pragma unroll
    for (int i = 0; i < 4; ++i) {
      float v = ps[i];
      v += __shfl_xor(v, 1);
      v += __shfl_xor(v, 2);
      v += __shfl_xor(v, 4);
      v += __shfl_xor(v, 8);
      if (r == 0) {
        int row = m0 + wr * 64 + m * 16 + q * 4 + i;
        atomicAdd(&tarval[row], v);
      }
    }
  }
}

// ---------------- scan: lambda-return reverse scan per batch row ------------
__global__ __launch_bounds__(64) void scan_kernel(
    const float* __restrict__ tarval, const float* __restrict__ reward,
    const float* __restrict__ cont, const float* __restrict__ voffset,
    const float* __restrict__ vscale, const float* __restrict__ b3,
    float* __restrict__ out) {
  __shared__ float tv[64];
  __shared__ float ret[64];
  const int b = blockIdx.x, t = threadIdx.x;  // t = 0..63 maps to orig t+1
  tv[t] = (tarval[b * 65 + 1 + t] + b3[0]) * vscale[0] + voffset[0];
  __syncthreads();
  if (t == 0) {
    float carry = tv[63];  // boot = tarval[:, -1]
    for (int j = 63; j >= 0; --j) {
      const int tt = j + 1;
      const float disc = cont[b * 65 + tt] * DISCF;
      const float r = reward[b * 65 + tt] + disc * ((1.0f - LAMF) * tv[j] + LAMF * carry);
      ret[j] = r;
      carry = r;
    }
  }
  __syncthreads();
  out[b * 64 + t] = ret[t];   // f32 output
}

extern "C" void kernel_launch(void* const* d_in, const int* in_sizes, int n_in,
                              void* d_out, int out_size, void* d_ws, size_t ws_size,
                              hipStream_t stream) {
  const float* feat    = (const float*)d_in[0];
  const float* reward  = (const float*)d_in[1];
  const float* cont    = (const float*)d_in[2];
  const float* voffset = (const float*)d_in[3];
  const float* vscale  = (const float*)d_in[4];
  const float* W1s = (const float*)d_in[11];
  const float* b1s = (const float*)d_in[12];
  const float* W2s = (const float*)d_in[13];
  const float* b2s = (const float*)d_in[14];
  const float* W3s = (const float*)d_in[15];
  const float* b3s = (const float*)d_in[16];

  char* ws = (char*)d_ws;
  unsigned short* Wt1 = (unsigned short*)ws;                   // 512 KB
  unsigned short* Wt2 = (unsigned short*)(ws + (512u << 10));  // 512 KB
  float* tarval       = (float*)(ws + (1024u << 10));          // 266 240 B
  unsigned short* H1  = (unsigned short*)(ws + (2048u << 10)); // 68 157 440 B

  prep_kernel<<<144, 256, 0, stream>>>(W1s, W2s, Wt1, Wt2, tarval);
  gemm1_kernel<<<RBLK * 4, 256, 0, stream>>>(feat, Wt1, b1s, H1);
  gemm2_kernel<<<RBLK * 4, 256, 0, stream>>>(H1, Wt2, b2s, W3s, tarval);
  scan_kernel<<<1024, 64, 0, stream>>>(tarval, reward, cont, voffset, vscale, b3s,
                                       (float*)d_out);
}

// Round 6
// 342.983 us; speedup vs baseline: 1.7269x; 1.0956x over previous
//
#include <hip/hip_runtime.h>
#include <stdint.h>

// B=1024, T=65, D=H=512. Only the SLOW critic feeds the output.
//   prep:  W1s,W2s -> bf16 transposed Wt[n][k]; zero tarval
//   gemm1: H1 = silu(feat @ W1s + b1s)           counted-vmcnt pipeline + swizzle
//   gemm2: tarval = silu(H1 @ W2s + b2s) @ W3s   same, fused W3 reduce
//   scan:  lambda-return reverse scan -> out (f32)
// K-loop: 2-deep lookahead, raw s_barrier, vmcnt(4/8) counted waits (T4),
// st-style XOR swizzle ((row&7)<<4) on LDS tiles (T2) -> conflict-free reads.

#define MROWS 66560   // 1024*65
#define RBLK 520      // MROWS/128
#define LAMF 0.95f
#define DISCF ((float)(1.0 - 1.0 / 333.0))

typedef __attribute__((ext_vector_type(8))) __bf16 bf16x8;
typedef __attribute__((ext_vector_type(4))) float f32x4;
typedef __attribute__((ext_vector_type(4))) unsigned int u32x4;

__device__ __forceinline__ unsigned short f2bf(float f) {
  unsigned int u = __float_as_uint(f);
  return (unsigned short)((u + 0x7FFFu + ((u >> 16) & 1u)) >> 16);
}
__device__ __forceinline__ float silu_f(float x) { return x / (1.0f + __expf(-x)); }

__device__ __forceinline__ void gload_lds16(const void* g, void* l) {
  __builtin_amdgcn_global_load_lds(
      (const __attribute__((address_space(1))) void*)g,
      (__attribute__((address_space(3))) void*)l, 16, 0, 0);
}

__device__ __forceinline__ u32x4 pack8(const f32x4& a, const f32x4& b) {
  union { unsigned short h[8]; u32x4 u; } p;
  p.h[0] = f2bf(a[0]); p.h[1] = f2bf(a[1]); p.h[2] = f2bf(a[2]); p.h[3] = f2bf(a[3]);
  p.h[4] = f2bf(b[0]); p.h[5] = f2bf(b[1]); p.h[6] = f2bf(b[2]); p.h[7] = f2bf(b[3]);
  return p.u;
}

// ---------------- prep: tiled transpose W->Wt bf16, zero tarval --------------
__global__ __launch_bounds__(256) void prep_kernel(
    const float* __restrict__ W1, const float* __restrict__ W2,
    unsigned short* __restrict__ Wt1, unsigned short* __restrict__ Wt2,
    float* __restrict__ tarval) {
  int b = blockIdx.x;
  if (b < 128) {
    const float* W = (b < 64) ? W1 : W2;
    unsigned short* Wt = (b < 64) ? Wt1 : Wt2;
    int tb = b & 63;
    int tk = (tb >> 3) * 64;
    int tn = (tb & 7) * 64;
    __shared__ float tile[64][65];
    int tx = threadIdx.x & 63;
    int ty4 = threadIdx.x >> 6;
#pragma unroll
    for (int i = 0; i < 16; ++i) {
      int row = ty4 * 16 + i;
      tile[row][tx] = W[(size_t)(tk + row) * 512 + tn + tx];
    }
    __syncthreads();
#pragma unroll
    for (int i = 0; i < 16; ++i) {
      int nrow = ty4 * 16 + i;
      Wt[(size_t)(tn + nrow) * 512 + tk + tx] = f2bf(tile[tx][nrow]);
    }
  } else {
    int id = (b - 128) * 256 + threadIdx.x;
#pragma unroll
    for (int i = 0; i < 17; ++i) {
      int idx = id + i * 4096;
      if (idx < MROWS) tarval[idx] = 0.0f;
    }
  }
}

// XCD-aware tile mapping: 4 col-blocks of one row-tile are consecutive per-XCD.
__device__ __forceinline__ void tile_map(int bid, int& rb, int& cb) {
  int xcd = bid & 7;
  int idx = bid >> 3;
  rb = xcd * 65 + (idx >> 2);
  cb = idx & 3;
}

// ---------------- GEMM1: A=feat f32 (reg convert), B=Wt1 bf16 ---------------
__global__ __launch_bounds__(256) void gemm1_kernel(
    const float* __restrict__ A, const unsigned short* __restrict__ Bt,
    const float* __restrict__ bias, unsigned short* __restrict__ Hout) {
  __shared__ __align__(16) unsigned char lds[65536];  // [2][A 16K | B 16K]

  int rb, cb; tile_map(blockIdx.x, rb, cb);
  const int m0 = rb * 128, n0 = cb * 128;
  const int tid = threadIdx.x;
  const int lane = tid & 63, w = tid >> 6;
  const int wr = w >> 1, wc = w & 1;
  const int q = lane >> 4, r = lane & 15;
  const unsigned int rx = (unsigned)(r & 7) << 4;          // read-side swizzle

  f32x4 acc[4][4] = {};
  f32x4 pa[8];

  // A reg-path source coords (unswizzled) + swizzled ds_write dest XOR
  const int a_row_off = tid >> 3;                           // + i*32
  const int a_col = (tid & 7) * 8;
  const unsigned int awx = ((unsigned)((tid >> 3) & 7)) << 4;
  // B gload path: linear dest, pre-swizzled global source
  const int b_row_off = w * 8 + (lane >> 3);                // + i*32
  const int b_col = ((lane & 7) ^ (lane >> 3)) * 8;

  // ---- prologue: pa(0); B(0)->bufB0; B(1)->bufB1; convert A(0)->bufA0 ----
#pragma unroll
  for (int i = 0; i < 4; ++i) {
    const float* s = A + (size_t)(m0 + i * 32 + a_row_off) * 512 + a_col;
    pa[2 * i] = *(const f32x4*)s; pa[2 * i + 1] = *(const f32x4*)(s + 4);
  }
#pragma unroll
  for (int i = 0; i < 4; ++i)
    gload_lds16(Bt + (size_t)(n0 + i * 32 + b_row_off) * 512 + b_col,
                lds + 16384 + i * 4096 + w * 1024);
#pragma unroll
  for (int i = 0; i < 4; ++i)
    gload_lds16(Bt + (size_t)(n0 + i * 32 + b_row_off) * 512 + 64 + b_col,
                lds + 49152 + i * 4096 + w * 1024);
#pragma unroll
  for (int i = 0; i < 4; ++i)   // compiler waits pa via counted vmcnt(8)
    *(u32x4*)(lds + ((unsigned)(i * 4096 + tid * 16) ^ awx)) =
        pack8(pa[2 * i], pa[2 * i + 1]);

#pragma unroll
  for (int t = 0; t < 8; ++t) {
    if (t < 7) asm volatile("s_waitcnt vmcnt(4) lgkmcnt(0)" ::: "memory");
    else       asm volatile("s_waitcnt vmcnt(0) lgkmcnt(0)" ::: "memory");
    __builtin_amdgcn_s_barrier();

    unsigned char* Acur = lds + (t & 1) * 32768;
    unsigned char* Bcur = Acur + 16384;

    if (t < 7) {   // pa(t+1): issue earliest (consumed at this iter's end)
      const int ks = (t + 1) * 64;
#pragma unroll
      for (int i = 0; i < 4; ++i) {
        const float* s = A + (size_t)(m0 + i * 32 + a_row_off) * 512 + ks + a_col;
        pa[2 * i] = *(const f32x4*)s; pa[2 * i + 1] = *(const f32x4*)(s + 4);
      }
    }

    // fragment reads (swizzled) -> regs
    bf16x8 af[2][4], bfr[2][4];
#pragma unroll
    for (int kk = 0; kk < 2; ++kk) {
      const unsigned int kb = kk * 64 + q * 16;
#pragma unroll
      for (int m = 0; m < 4; ++m) {
        const unsigned int row = wr * 64 + m * 16 + r;
        af[kk][m] = *(const bf16x8*)(Acur + ((row * 128 + kb) ^ rx));
      }
#pragma unroll
      for (int n = 0; n < 4; ++n) {
        const unsigned int row = wc * 64 + n * 16 + r;
        bfr[kk][n] = *(const bf16x8*)(Bcur + ((row * 128 + kb) ^ rx));
      }
    }
    asm volatile("s_waitcnt lgkmcnt(0)" ::: "memory");
    __builtin_amdgcn_sched_barrier(0);
    __builtin_amdgcn_s_barrier();     // all waves done reading buf[t&1]

    if (t + 2 < 8) {                  // B(t+2) -> bufB[t&1] (2-ahead, counted)
      const int ks = (t + 2) * 64;
#pragma unroll
      for (int i = 0; i < 4; ++i)
        gload_lds16(Bt + (size_t)(n0 + i * 32 + b_row_off) * 512 + ks + b_col,
                    Bcur + i * 4096 + w * 1024);
    }
    if (t < 7) {                      // convert+write A(t+1) -> bufA[(t+1)&1]
      unsigned char* Anx = lds + ((t + 1) & 1) * 32768;
#pragma unroll
      for (int i = 0; i < 4; ++i)
        *(u32x4*)(Anx + ((unsigned)(i * 4096 + tid * 16) ^ awx)) =
            pack8(pa[2 * i], pa[2 * i + 1]);
    }

#pragma unroll
    for (int kk = 0; kk < 2; ++kk)
#pragma unroll
      for (int m = 0; m < 4; ++m)
#pragma unroll
        for (int n = 0; n < 4; ++n)
          acc[m][n] = __builtin_amdgcn_mfma_f32_16x16x32_bf16(af[kk][m], bfr[kk][n], acc[m][n], 0, 0, 0);
  }

  // epilogue: bias + silu -> bf16 H1
#pragma unroll
  for (int n = 0; n < 4; ++n) {
    const int col = n0 + wc * 64 + n * 16 + r;
    const float bn = bias[col];
#pragma unroll
    for (int m = 0; m < 4; ++m) {
      const int rbase = m0 + wr * 64 + m * 16 + q * 4;
#pragma unroll
      for (int i = 0; i < 4; ++i)
        Hout[(size_t)(rbase + i) * 512 + col] = f2bf(silu_f(acc[m][n][i] + bn));
    }
  }
}

// ---------------- GEMM2: A=H1 bf16, B=Wt2 bf16, fused W3 reduce -------------
__global__ __launch_bounds__(256) void gemm2_kernel(
    const unsigned short* __restrict__ A, const unsigned short* __restrict__ Bt,
    const float* __restrict__ bias, const float* __restrict__ W3,
    float* __restrict__ tarval) {
  __shared__ __align__(16) unsigned char lds[65536];

  int rb, cb; tile_map(blockIdx.x, rb, cb);
  const int m0 = rb * 128, n0 = cb * 128;
  const int tid = threadIdx.x;
  const int lane = tid & 63, w = tid >> 6;
  const int wr = w >> 1, wc = w & 1;
  const int q = lane >> 4, r = lane & 15;
  const unsigned int rx = (unsigned)(r & 7) << 4;

  f32x4 acc[4][4] = {};
  const int s_row_off = w * 8 + (lane >> 3);                // + i*32
  const int s_col = ((lane & 7) ^ (lane >> 3)) * 8;

  // ---- prologue: stage(0)->buf0, stage(1)->buf1 (8 gloads each) ----
#pragma unroll
  for (int i = 0; i < 4; ++i) {
    gload_lds16(A  + (size_t)(m0 + i * 32 + s_row_off) * 512 + s_col,
                lds + i * 4096 + w * 1024);
    gload_lds16(Bt + (size_t)(n0 + i * 32 + s_row_off) * 512 + s_col,
                lds + 16384 + i * 4096 + w * 1024);
  }
#pragma unroll
  for (int i = 0; i < 4; ++i) {
    gload_lds16(A  + (size_t)(m0 + i * 32 + s_row_off) * 512 + 64 + s_col,
                lds + 32768 + i * 4096 + w * 1024);
    gload_lds16(Bt + (size_t)(n0 + i * 32 + s_row_off) * 512 + 64 + s_col,
                lds + 49152 + i * 4096 + w * 1024);
  }

#pragma unroll
  for (int t = 0; t < 8; ++t) {
    if (t < 7) asm volatile("s_waitcnt vmcnt(8) lgkmcnt(0)" ::: "memory");
    else       asm volatile("s_waitcnt vmcnt(0) lgkmcnt(0)" ::: "memory");
    __builtin_amdgcn_s_barrier();

    unsigned char* Acur = lds + (t & 1) * 32768;
    unsigned char* Bcur = Acur + 16384;

    bf16x8 af[2][4], bfr[2][4];
#pragma unroll
    for (int kk = 0; kk < 2; ++kk) {
      const unsigned int kb = kk * 64 + q * 16;
#pragma unroll
      for (int m = 0; m < 4; ++m) {
        const unsigned int row = wr * 64 + m * 16 + r;
        af[kk][m] = *(const bf16x8*)(Acur + ((row * 128 + kb) ^ rx));
      }
#pragma unroll
      for (int n = 0; n < 4; ++n) {
        const unsigned int row = wc * 64 + n * 16 + r;
        bfr[kk][n] = *(const bf16x8*)(Bcur + ((row * 128 + kb) ^ rx));
      }
    }
    asm volatile("s_waitcnt lgkmcnt(0)" ::: "memory");
    __builtin_amdgcn_sched_barrier(0);
    __builtin_amdgcn_s_barrier();

    if (t + 2 < 8) {                  // stage(t+2) -> buf[t&1]
      const int ks = (t + 2) * 64;
#pragma unroll
      for (int i = 0; i < 4; ++i) {
        gload_lds16(A  + (size_t)(m0 + i * 32 + s_row_off) * 512 + ks + s_col,
                    Acur + i * 4096 + w * 1024);
        gload_lds16(Bt + (size_t)(n0 + i * 32 + s_row_off) * 512 + ks + s_col,
                    Bcur + i * 4096 + w * 1024);
      }
    }

#pragma unroll
    for (int kk = 0; kk < 2; ++kk)
#pragma unroll
      for (int m = 0; m < 4; ++m)
#pragma unroll
        for (int n = 0; n < 4; ++n)
          acc[m][n] = __builtin_amdgcn_mfma_f32_16x16x32_bf16(af[kk][m], bfr[kk][n], acc[m][n], 0, 0, 0);
  }

  // epilogue: silu(acc+b2) * W3[col], 16-lane shuffle reduce, atomic per row
#pragma unroll
  for (int m = 0; m < 4; ++m) {
    float ps0 = 0.f, ps1 = 0.f, ps2 = 0.f, ps3 = 0.f;
#pragma unroll
    for (int n = 0; n < 4; ++n) {
      const int col = n0 + wc * 64 + n * 16 + r;
      const float bn = bias[col];
      const float w3 = W3[col];
      ps0 += silu_f(acc[m][n][0] + bn) * w3;
      ps1 += silu_f(acc[m][n][1] + bn) * w3;
      ps2 += silu_f(acc[m][n][2] + bn) * w3;
      ps3 += silu_f(acc[m][n][3] + bn) * w3;
    }
    float ps[4] = {ps0, ps1, ps2, ps3};
#pragma unroll
    for (int i = 0; i < 4; ++i) {
      float v = ps[i];
      v += __shfl_xor(v, 1);
      v += __shfl_xor(v, 2);
      v += __shfl_xor(v, 4);
      v += __shfl_xor(v, 8);
      if (r == 0) {
        int row = m0 + wr * 64 + m * 16 + q * 4 + i;
        atomicAdd(&tarval[row], v);
      }
    }
  }
}

// ---------------- scan: lambda-return reverse scan per batch row ------------
__global__ __launch_bounds__(64) void scan_kernel(
    const float* __restrict__ tarval, const float* __restrict__ reward,
    const float* __restrict__ cont, const float* __restrict__ voffset,
    const float* __restrict__ vscale, const float* __restrict__ b3,
    float* __restrict__ out) {
  __shared__ float tv[64];
  __shared__ float ret[64];
  const int b = blockIdx.x, t = threadIdx.x;
  tv[t] = (tarval[b * 65 + 1 + t] + b3[0]) * vscale[0] + voffset[0];
  __syncthreads();
  if (t == 0) {
    float carry = tv[63];
    for (int j = 63; j >= 0; --j) {
      const int tt = j + 1;
      const float disc = cont[b * 65 + tt] * DISCF;
      const float r = reward[b * 65 + tt] + disc * ((1.0f - LAMF) * tv[j] + LAMF * carry);
      ret[j] = r;
      carry = r;
    }
  }
  __syncthreads();
  out[b * 64 + t] = ret[t];
}

extern "C" void kernel_launch(void* const* d_in, const int* in_sizes, int n_in,
                              void* d_out, int out_size, void* d_ws, size_t ws_size,
                              hipStream_t stream) {
  const float* feat    = (const float*)d_in[0];
  const float* reward  = (const float*)d_in[1];
  const float* cont    = (const float*)d_in[2];
  const float* voffset = (const float*)d_in[3];
  const float* vscale  = (const float*)d_in[4];
  const float* W1s = (const float*)d_in[11];
  const float* b1s = (const float*)d_in[12];
  const float* W2s = (const float*)d_in[13];
  const float* b2s = (const float*)d_in[14];
  const float* W3s = (const float*)d_in[15];
  const float* b3s = (const float*)d_in[16];

  char* ws = (char*)d_ws;
  unsigned short* Wt1 = (unsigned short*)ws;                   // 512 KB
  unsigned short* Wt2 = (unsigned short*)(ws + (512u << 10));  // 512 KB
  float* tarval       = (float*)(ws + (1024u << 10));          // 266 240 B
  unsigned short* H1  = (unsigned short*)(ws + (2048u << 10)); // 68 157 440 B

  prep_kernel<<<144, 256, 0, stream>>>(W1s, W2s, Wt1, Wt2, tarval);
  gemm1_kernel<<<RBLK * 4, 256, 0, stream>>>(feat, Wt1, b1s, H1);
  gemm2_kernel<<<RBLK * 4, 256, 0, stream>>>(H1, Wt2, b2s, W3s, tarval);
  scan_kernel<<<1024, 64, 0, stream>>>(tarval, reward, cont, voffset, vscale, b3s,
                                       (float*)d_out);
}